// Round 1
// baseline (940.910 us; speedup 1.0000x reference)
//
#include <hip/hip_runtime.h>
#include <cstdint>
#include <cstddef>

// Problem dims (fixed by setup_inputs)
#define HDIM 1024
#define EEXP 16
#define BATCH 2048
#define MROWS (BATCH * EEXP)   // 32768
#define NHEADS 8
#define HEADD 128
#define KDIM 1024
#define LN_EPS 1e-5f

typedef __bf16 bf16x8_t __attribute__((ext_vector_type(8)));
typedef float f32x4_t __attribute__((ext_vector_type(4)));
typedef unsigned short u16x4_t __attribute__((ext_vector_type(4)));
typedef unsigned short u16x8_t __attribute__((ext_vector_type(8)));

__device__ __forceinline__ unsigned short f2bf(float f) {
    unsigned int u = __builtin_bit_cast(unsigned int, f);
    unsigned int r = (u + 0x7FFFu + ((u >> 16) & 1u)) >> 16;  // RNE
    return (unsigned short)r;
}
__device__ __forceinline__ float bf2f(unsigned short h) {
    unsigned int u = ((unsigned int)h) << 16;
    return __builtin_bit_cast(float, u);
}

// ---------------------------------------------------------------------------
// fp32 -> bf16 conversion (weights). n must be a multiple of 1024.
// ---------------------------------------------------------------------------
__global__ __launch_bounds__(256) void k_conv(const float* __restrict__ src,
                                              unsigned short* __restrict__ dst,
                                              int n) {
    int i = (blockIdx.x * 256 + threadIdx.x) * 4;
    if (i >= n) return;
    float4 v = *(const float4*)(src + i);
    u16x4_t o;
    o.x = f2bf(v.x); o.y = f2bf(v.y); o.z = f2bf(v.z); o.w = f2bf(v.w);
    *(u16x4_t*)(dst + i) = o;
}

// ---------------------------------------------------------------------------
// comm (chain graph) + LayerNorm -> xn (bf16).  One block per row (b,e).
// comm[b,e,:] = 0.5*x[b,e-1,:] + 0.5*x[b,e+1,:]
// ---------------------------------------------------------------------------
__global__ __launch_bounds__(256) void k_prep(const float* __restrict__ x,
                                              const float* __restrict__ lng,
                                              const float* __restrict__ lnb,
                                              unsigned short* __restrict__ xn) {
    const int m = blockIdx.x;
    const int e = m & (EEXP - 1);
    const int t = threadIdx.x;
    const int h = t * 4;
    const float* xr = x + (size_t)m * HDIM;

    float c0 = 0.f, c1 = 0.f, c2 = 0.f, c3 = 0.f;
    if (e > 0) {
        float4 v = *(const float4*)(xr - HDIM + h);
        c0 = 0.5f * v.x; c1 = 0.5f * v.y; c2 = 0.5f * v.z; c3 = 0.5f * v.w;
    }
    if (e < EEXP - 1) {
        float4 v = *(const float4*)(xr + HDIM + h);
        c0 += 0.5f * v.x; c1 += 0.5f * v.y; c2 += 0.5f * v.z; c3 += 0.5f * v.w;
    }
    float s  = c0 + c1 + c2 + c3;
    float ss = c0 * c0 + c1 * c1 + c2 * c2 + c3 * c3;
#pragma unroll
    for (int off = 32; off; off >>= 1) {
        s  += __shfl_xor(s, off, 64);
        ss += __shfl_xor(ss, off, 64);
    }
    __shared__ float red[8];
    const int wv = t >> 6;
    if ((t & 63) == 0) { red[wv] = s; red[4 + wv] = ss; }
    __syncthreads();
    s  = red[0] + red[1] + red[2] + red[3];
    ss = red[4] + red[5] + red[6] + red[7];
    const float mean = s * (1.0f / HDIM);
    const float var  = ss * (1.0f / HDIM) - mean * mean;
    const float rinv = rsqrtf(var + LN_EPS);

    float4 g = *(const float4*)(lng + h);
    float4 b = *(const float4*)(lnb + h);
    u16x4_t o;
    o.x = f2bf((c0 - mean) * rinv * g.x + b.x);
    o.y = f2bf((c1 - mean) * rinv * g.y + b.y);
    o.z = f2bf((c2 - mean) * rinv * g.z + b.z);
    o.w = f2bf((c3 - mean) * rinv * g.w + b.w);
    *(u16x4_t*)(xn + (size_t)m * HDIM + h) = o;
}

// ---------------------------------------------------------------------------
// m97-style bf16 GEMM, C[m,n] = sum_k A[m,k] * W[n,k]   (B^T layout).
// 128x128 tile, BK=32, 256 threads (4 waves, 2x2 of 64x64), mfma 16x16x32.
// QKV variant: +bias, bf16 out [M,3072].  O variant: +bias, fp32 out [M,1024].
// ---------------------------------------------------------------------------
template <int N, bool IS_QKV>
__global__ __launch_bounds__(256) void k_gemm(
    const unsigned short* __restrict__ A,   // [M, K] bf16
    const unsigned short* __restrict__ Bw,  // [N, K] bf16
    const float* __restrict__ b0,           // bias (bq or bo)
    const float* __restrict__ b1,           // bk (QKV only)
    const float* __restrict__ b2,           // bv (QKV only)
    unsigned short* __restrict__ Cbf,       // QKV output
    float* __restrict__ Cf) {               // O output
    constexpr int K = KDIM;
    constexpr int MTILES = MROWS / 128;
    __shared__ unsigned short As[128 * 32];
    __shared__ unsigned short Bs[128 * 32];

    const int tid  = threadIdx.x;
    const int mt   = blockIdx.x % MTILES;
    const int nt   = blockIdx.x / MTILES;
    const int m0   = mt * 128, n0 = nt * 128;
    const int lane = tid & 63, wave = tid >> 6;
    const int wm   = (wave >> 1) * 64, wn = (wave & 1) * 64;
    const int quad = lane >> 4, r16 = lane & 15;
    // staging: thread -> 16B chunk; chunk c covers tile row c/4, k-chunk (c%4)*8
    const int srow = tid >> 2, skk = (tid & 3) * 8;

    f32x4_t acc[4][4];
#pragma unroll
    for (int i = 0; i < 4; i++)
#pragma unroll
        for (int j = 0; j < 4; j++) acc[i][j] = f32x4_t{0.f, 0.f, 0.f, 0.f};

    const unsigned short* Ag = A + (size_t)(m0 + srow) * K + skk;
    const unsigned short* Bg = Bw + (size_t)(n0 + srow) * K + skk;

    for (int k0 = 0; k0 < K; k0 += 32) {
        __syncthreads();  // previous iteration's LDS reads complete
        __builtin_amdgcn_global_load_lds(
            (const __attribute__((address_space(1))) void*)(Ag + k0),
            (__attribute__((address_space(3))) void*)(As + tid * 8), 16, 0, 0);
        __builtin_amdgcn_global_load_lds(
            (const __attribute__((address_space(1))) void*)(Ag + (size_t)64 * K + k0),
            (__attribute__((address_space(3))) void*)(As + 2048 + tid * 8), 16, 0, 0);
        __builtin_amdgcn_global_load_lds(
            (const __attribute__((address_space(1))) void*)(Bg + k0),
            (__attribute__((address_space(3))) void*)(Bs + tid * 8), 16, 0, 0);
        __builtin_amdgcn_global_load_lds(
            (const __attribute__((address_space(1))) void*)(Bg + (size_t)64 * K + k0),
            (__attribute__((address_space(3))) void*)(Bs + 2048 + tid * 8), 16, 0, 0);
        __syncthreads();  // vmcnt(0) drain -> tiles resident

        bf16x8_t a[4], b[4];
#pragma unroll
        for (int i = 0; i < 4; i++)
            a[i] = *(const bf16x8_t*)&As[(wm + i * 16 + r16) * 32 + quad * 8];
#pragma unroll
        for (int j = 0; j < 4; j++)
            b[j] = *(const bf16x8_t*)&Bs[(wn + j * 16 + r16) * 32 + quad * 8];
#pragma unroll
        for (int i = 0; i < 4; i++)
#pragma unroll
            for (int j = 0; j < 4; j++)
                acc[i][j] = __builtin_amdgcn_mfma_f32_16x16x32_bf16(a[i], b[j], acc[i][j], 0, 0, 0);
    }

    // Epilogue. C/D layout: col = lane&15, row = quad*4 + reg  [m89-verified]
#pragma unroll
    for (int j = 0; j < 4; j++) {
        const int gcol = n0 + wn + j * 16 + r16;
        float bias;
        if constexpr (IS_QKV) {
            bias = (gcol < 1024) ? b0[gcol] : (gcol < 2048 ? b1[gcol - 1024] : b2[gcol - 2048]);
        } else {
            bias = b0[gcol];
        }
#pragma unroll
        for (int i = 0; i < 4; i++) {
#pragma unroll
            for (int reg = 0; reg < 4; reg++) {
                const int grow = m0 + wm + i * 16 + quad * 4 + reg;
                const float v = acc[i][j][reg] + bias;
                if constexpr (IS_QKV) {
                    Cbf[(size_t)grow * N + gcol] = f2bf(v);
                } else {
                    Cf[(size_t)grow * N + gcol] = v;
                }
            }
        }
    }
}

// ---------------------------------------------------------------------------
// Attention over E=16 per (b, head).  One block per (b*NHEADS + n).
// qkv layout: [M, 3H], q at col n*128+d, k at H+..., v at 2H+...
// Writes attended bf16 [M, H] with h = n*128 + d.
// ---------------------------------------------------------------------------
__global__ __launch_bounds__(256) void k_attn(const unsigned short* __restrict__ qkv,
                                              unsigned short* __restrict__ att) {
    const int bidx = blockIdx.x;
    const int b = bidx >> 3, n = bidx & 7;
    __shared__ float qs[16][132], ks[16][132], vs[16][132];  // pad 132: 2-way max
    __shared__ float ps[16][17];
    const int t = threadIdx.x;

    // load q/k/v tiles: thread t -> row t>>4, 8 cols starting (t&15)*8
    {
        const int row = t >> 4, c0 = (t & 15) * 8;
        const size_t base = (size_t)(b * EEXP + row) * (3 * HDIM) + n * HEADD + c0;
        u16x8_t qv = *(const u16x8_t*)&qkv[base];
        u16x8_t kv = *(const u16x8_t*)&qkv[base + HDIM];
        u16x8_t vv = *(const u16x8_t*)&qkv[base + 2 * HDIM];
#pragma unroll
        for (int u = 0; u < 8; u++) {
            qs[row][c0 + u] = bf2f(qv[u]);
            ks[row][c0 + u] = bf2f(kv[u]);
            vs[row][c0 + u] = bf2f(vv[u]);
        }
    }
    __syncthreads();

    // scores + softmax: thread t owns (qe = t>>4, ke = t&15)
    const int qe = t >> 4, ke = t & 15;
    float s = 0.f;
#pragma unroll 8
    for (int d = 0; d < HEADD; d += 4) {
        s += qs[qe][d] * ks[ke][d] + qs[qe][d + 1] * ks[ke][d + 1] +
             qs[qe][d + 2] * ks[ke][d + 2] + qs[qe][d + 3] * ks[ke][d + 3];
    }
    s *= 0.08838834764831845f;  // 1/sqrt(128)
    float mx = s;
#pragma unroll
    for (int off = 8; off; off >>= 1) mx = fmaxf(mx, __shfl_xor(mx, off, 16));
    const float ex = __expf(s - mx);
    float sum = ex;
#pragma unroll
    for (int off = 8; off; off >>= 1) sum += __shfl_xor(sum, off, 16);
    ps[qe][ke] = ex / sum;
    __syncthreads();

    // attended[qe][d] = sum_ke p * v ; thread t: qe = t>>4, d = (t&15) + 16u
    const int dd = t & 15;
    float o[8] = {0.f, 0.f, 0.f, 0.f, 0.f, 0.f, 0.f, 0.f};
#pragma unroll
    for (int k2 = 0; k2 < EEXP; k2++) {
        const float p = ps[qe][k2];
#pragma unroll
        for (int u = 0; u < 8; u++) o[u] += p * vs[k2][dd + 16 * u];
    }
    const size_t ob = (size_t)(b * EEXP + qe) * HDIM + n * HEADD + dd;
#pragma unroll
    for (int u = 0; u < 8; u++) att[ob + 16 * u] = f2bf(o[u]);
}

// ---------------------------------------------------------------------------
// Residual + gate + blend.  One block per row.  In-place on d_out, which holds
// attended@wo^T + bo.  comm_out = that + 0.5*(x[e-1]+x[e+1]); gate = sigmoid(
// dot(x,wg[:H]) + dot(comm_out,wg[H:]) + bg); out = gate*comm_out+(1-gate)*x.
// ---------------------------------------------------------------------------
__global__ __launch_bounds__(256) void k_gate(const float* __restrict__ x,
                                              const float* __restrict__ wg,
                                              const float* __restrict__ bg,
                                              float* __restrict__ out) {
    const int m = blockIdx.x;
    const int e = m & (EEXP - 1);
    const int t = threadIdx.x;
    const int h = t * 4;
    const float* xr = x + (size_t)m * HDIM;
    float* orow = out + (size_t)m * HDIM;

    float4 xv = *(const float4*)(xr + h);
    float4 rv = *(const float4*)(orow + h);
    float c0 = 0.f, c1 = 0.f, c2 = 0.f, c3 = 0.f;
    if (e > 0) {
        float4 v = *(const float4*)(xr - HDIM + h);
        c0 = 0.5f * v.x; c1 = 0.5f * v.y; c2 = 0.5f * v.z; c3 = 0.5f * v.w;
    }
    if (e < EEXP - 1) {
        float4 v = *(const float4*)(xr + HDIM + h);
        c0 += 0.5f * v.x; c1 += 0.5f * v.y; c2 += 0.5f * v.z; c3 += 0.5f * v.w;
    }
    const float co0 = rv.x + c0, co1 = rv.y + c1, co2 = rv.z + c2, co3 = rv.w + c3;

    float4 w1 = *(const float4*)(wg + h);
    float4 w2 = *(const float4*)(wg + HDIM + h);
    float d = xv.x * w1.x + xv.y * w1.y + xv.z * w1.z + xv.w * w1.w +
              co0 * w2.x + co1 * w2.y + co2 * w2.z + co3 * w2.w;
#pragma unroll
    for (int off = 32; off; off >>= 1) d += __shfl_xor(d, off, 64);
    __shared__ float red[4];
    const int wv = t >> 6;
    if ((t & 63) == 0) red[wv] = d;
    __syncthreads();
    const float tot = red[0] + red[1] + red[2] + red[3] + bg[0];
    const float gate = 1.0f / (1.0f + __expf(-tot));

    float4 ov;
    ov.x = gate * co0 + (1.0f - gate) * xv.x;
    ov.y = gate * co1 + (1.0f - gate) * xv.y;
    ov.z = gate * co2 + (1.0f - gate) * xv.z;
    ov.w = gate * co3 + (1.0f - gate) * xv.w;
    *(float4*)(orow + h) = ov;
}

// ---------------------------------------------------------------------------
extern "C" void kernel_launch(void* const* d_in, const int* in_sizes, int n_in,
                              void* d_out, int out_size, void* d_ws, size_t ws_size,
                              hipStream_t stream) {
    const float* x   = (const float*)d_in[0];
    const float* lng = (const float*)d_in[1];
    const float* lnb = (const float*)d_in[2];
    const float* wq  = (const float*)d_in[3];
    const float* bq  = (const float*)d_in[4];
    const float* wk  = (const float*)d_in[5];
    const float* bk  = (const float*)d_in[6];
    const float* wv  = (const float*)d_in[7];
    const float* bv  = (const float*)d_in[8];
    const float* wo  = (const float*)d_in[9];
    const float* bo  = (const float*)d_in[10];
    const float* wg  = (const float*)d_in[11];
    const float* bg  = (const float*)d_in[12];
    float* out = (float*)d_out;

    // workspace layout (bf16 buffers), total ~344 MB
    unsigned short* wqkv = (unsigned short*)d_ws;                 // [3072,1024]
    unsigned short* wob  = wqkv + (size_t)3072 * 1024;            // [1024,1024]
    unsigned short* xn   = wob + (size_t)1024 * 1024;             // [M,1024]
    unsigned short* qkv  = xn + (size_t)MROWS * HDIM;             // [M,3072]
    unsigned short* att  = qkv + (size_t)MROWS * 3 * HDIM;        // [M,1024]

    const int WELTS = 1024 * 1024;
    k_conv<<<WELTS / 1024, 256, 0, stream>>>(wq, wqkv, WELTS);
    k_conv<<<WELTS / 1024, 256, 0, stream>>>(wk, wqkv + (size_t)WELTS, WELTS);
    k_conv<<<WELTS / 1024, 256, 0, stream>>>(wv, wqkv + (size_t)2 * WELTS, WELTS);
    k_conv<<<WELTS / 1024, 256, 0, stream>>>(wo, wob, WELTS);

    k_prep<<<MROWS, 256, 0, stream>>>(x, lng, lnb, xn);

    k_gemm<3072, true><<<(MROWS / 128) * (3072 / 128), 256, 0, stream>>>(
        xn, wqkv, bq, bk, bv, qkv, nullptr);

    k_attn<<<BATCH * NHEADS, 256, 0, stream>>>(qkv, att);

    k_gemm<1024, false><<<(MROWS / 128) * (1024 / 128), 256, 0, stream>>>(
        att, wob, bo, nullptr, nullptr, nullptr, out);

    k_gate<<<MROWS, 256, 0, stream>>>(x, wg, bg, out);
}

// Round 2
// 817.113 us; speedup vs baseline: 1.1515x; 1.1515x over previous
//
#include <hip/hip_runtime.h>
#include <cstdint>
#include <cstddef>

// Problem dims (fixed by setup_inputs)
#define HDIM 1024
#define EEXP 16
#define BATCH 2048
#define MROWS (BATCH * EEXP)   // 32768
#define NHEADS 8
#define HEADD 128
#define KDIM 1024
#define LN_EPS 1e-5f

typedef __bf16 bf16x8_t __attribute__((ext_vector_type(8)));
typedef float f32x4_t __attribute__((ext_vector_type(4)));
typedef unsigned short u16x4_t __attribute__((ext_vector_type(4)));
typedef unsigned short u16x8_t __attribute__((ext_vector_type(8)));

__device__ __forceinline__ unsigned short f2bf(float f) {
    unsigned int u = __builtin_bit_cast(unsigned int, f);
    unsigned int r = (u + 0x7FFFu + ((u >> 16) & 1u)) >> 16;  // RNE
    return (unsigned short)r;
}
__device__ __forceinline__ float bf2f(unsigned short h) {
    unsigned int u = ((unsigned int)h) << 16;
    return __builtin_bit_cast(float, u);
}

// ---------------------------------------------------------------------------
// fp32 -> bf16 conversion for all 4 weight matrices in one launch.
// 1024 blocks per matrix (1M elements each, 4 per thread).
// ---------------------------------------------------------------------------
__global__ __launch_bounds__(256) void k_conv4(
    const float* __restrict__ s0, const float* __restrict__ s1,
    const float* __restrict__ s2, const float* __restrict__ s3,
    unsigned short* __restrict__ d0, unsigned short* __restrict__ d1,
    unsigned short* __restrict__ d2, unsigned short* __restrict__ d3) {
    const int which = blockIdx.x >> 10;
    const int i = ((blockIdx.x & 1023) * 256 + threadIdx.x) * 4;
    const float* s = (which == 0) ? s0 : (which == 1) ? s1 : (which == 2) ? s2 : s3;
    unsigned short* d = (which == 0) ? d0 : (which == 1) ? d1 : (which == 2) ? d2 : d3;
    float4 v = *(const float4*)(s + i);
    u16x4_t o;
    o.x = f2bf(v.x); o.y = f2bf(v.y); o.z = f2bf(v.z); o.w = f2bf(v.w);
    *(u16x4_t*)(d + i) = o;
}

// ---------------------------------------------------------------------------
// comm (chain graph) + LayerNorm -> xn (bf16).  One block per row (b,e).
// comm[b,e,:] = 0.5*x[b,e-1,:] + 0.5*x[b,e+1,:]
// ---------------------------------------------------------------------------
__global__ __launch_bounds__(256) void k_prep(const float* __restrict__ x,
                                              const float* __restrict__ lng,
                                              const float* __restrict__ lnb,
                                              unsigned short* __restrict__ xn) {
    const int m = blockIdx.x;
    const int e = m & (EEXP - 1);
    const int t = threadIdx.x;
    const int h = t * 4;
    const float* xr = x + (size_t)m * HDIM;

    float c0 = 0.f, c1 = 0.f, c2 = 0.f, c3 = 0.f;
    if (e > 0) {
        float4 v = *(const float4*)(xr - HDIM + h);
        c0 = 0.5f * v.x; c1 = 0.5f * v.y; c2 = 0.5f * v.z; c3 = 0.5f * v.w;
    }
    if (e < EEXP - 1) {
        float4 v = *(const float4*)(xr + HDIM + h);
        c0 += 0.5f * v.x; c1 += 0.5f * v.y; c2 += 0.5f * v.z; c3 += 0.5f * v.w;
    }
    float s  = c0 + c1 + c2 + c3;
    float ss = c0 * c0 + c1 * c1 + c2 * c2 + c3 * c3;
#pragma unroll
    for (int off = 32; off; off >>= 1) {
        s  += __shfl_xor(s, off, 64);
        ss += __shfl_xor(ss, off, 64);
    }
    __shared__ float red[8];
    const int wv = t >> 6;
    if ((t & 63) == 0) { red[wv] = s; red[4 + wv] = ss; }
    __syncthreads();
    s  = red[0] + red[1] + red[2] + red[3];
    ss = red[4] + red[5] + red[6] + red[7];
    const float mean = s * (1.0f / HDIM);
    const float var  = ss * (1.0f / HDIM) - mean * mean;
    const float rinv = rsqrtf(var + LN_EPS);

    float4 g = *(const float4*)(lng + h);
    float4 b = *(const float4*)(lnb + h);
    u16x4_t o;
    o.x = f2bf((c0 - mean) * rinv * g.x + b.x);
    o.y = f2bf((c1 - mean) * rinv * g.y + b.y);
    o.z = f2bf((c2 - mean) * rinv * g.z + b.z);
    o.w = f2bf((c3 - mean) * rinv * g.w + b.w);
    *(u16x4_t*)(xn + (size_t)m * HDIM + h) = o;
}

// ---------------------------------------------------------------------------
// bf16 GEMM, C[m,n] = sum_k A[m,k] * W[n,k]   (B^T layout).
// 128x128 tile, BK=32, 256 threads (4 waves in 2x2 of 64x64), mfma 16x16x32.
// MFMA operands SWAPPED (mfma(b,a)): lane holds one M-row (r16) and 4
// consecutive N-cols (quad*4+reg) -> packed dwordx2/dwordx4 epilogue stores.
// LDS k-chunk XOR-swizzled by (row>>1)&3 -> 2-way-max bank access on ds_read.
// ---------------------------------------------------------------------------
template <int N, bool IS_QKV>
__global__ __launch_bounds__(256) void k_gemm(
    const unsigned short* __restrict__ A,   // [M, K] bf16
    const unsigned short* __restrict__ Bw,  // [N, K] bf16
    const float* __restrict__ b0,           // bias (bq or bo)
    const float* __restrict__ b1,           // bk (QKV only)
    const float* __restrict__ b2,           // bv (QKV only)
    unsigned short* __restrict__ Cbf,       // QKV output
    float* __restrict__ Cf) {               // O output
    constexpr int K = KDIM;
    constexpr int NTILES = N / 128;
    __shared__ unsigned short As[128 * 32];
    __shared__ unsigned short Bs[128 * 32];

    const int tid  = threadIdx.x;
    const int nt   = blockIdx.x % NTILES;   // nt fast: concurrent blocks share A tile
    const int mt   = blockIdx.x / NTILES;
    const int m0   = mt * 128, n0 = nt * 128;
    const int lane = tid & 63, wave = tid >> 6;
    const int wm   = (wave >> 1) * 64, wn = (wave & 1) * 64;
    const int quad = lane >> 4, r16 = lane & 15;
    // staging: thread -> 16B chunk of row srow; source k-chunk XOR-swizzled so
    // that LDS (lane-contiguous dest, m104 caveat) ends up swizzled by row.
    const int srow = tid >> 2;
    const int skk  = (((tid & 3) ^ ((srow >> 1) & 3)) * 8);
    // ds_read physical slot for chunk `quad` of row (.. + r16): lane-constant
    const int slot = (quad ^ ((r16 >> 1) & 3)) * 8;

    f32x4_t acc[4][4];
#pragma unroll
    for (int i = 0; i < 4; i++)
#pragma unroll
        for (int j = 0; j < 4; j++) acc[i][j] = f32x4_t{0.f, 0.f, 0.f, 0.f};

    const unsigned short* Ag = A + (size_t)(m0 + srow) * K + skk;
    const unsigned short* Bg = Bw + (size_t)(n0 + srow) * K + skk;

    for (int k0 = 0; k0 < K; k0 += 32) {
        __syncthreads();  // previous iteration's LDS reads complete
        __builtin_amdgcn_global_load_lds(
            (const __attribute__((address_space(1))) void*)(Ag + k0),
            (__attribute__((address_space(3))) void*)(As + tid * 8), 16, 0, 0);
        __builtin_amdgcn_global_load_lds(
            (const __attribute__((address_space(1))) void*)(Ag + (size_t)64 * K + k0),
            (__attribute__((address_space(3))) void*)(As + 2048 + tid * 8), 16, 0, 0);
        __builtin_amdgcn_global_load_lds(
            (const __attribute__((address_space(1))) void*)(Bg + k0),
            (__attribute__((address_space(3))) void*)(Bs + tid * 8), 16, 0, 0);
        __builtin_amdgcn_global_load_lds(
            (const __attribute__((address_space(1))) void*)(Bg + (size_t)64 * K + k0),
            (__attribute__((address_space(3))) void*)(Bs + 2048 + tid * 8), 16, 0, 0);
        __syncthreads();  // vmcnt(0) drain -> tiles resident

        bf16x8_t a[4], b[4];
#pragma unroll
        for (int i = 0; i < 4; i++)
            a[i] = *(const bf16x8_t*)&As[(wm + i * 16 + r16) * 32 + slot];
#pragma unroll
        for (int j = 0; j < 4; j++)
            b[j] = *(const bf16x8_t*)&Bs[(wn + j * 16 + r16) * 32 + slot];
        // swapped operands: D[m=lane&15][n=quad*4+reg]
#pragma unroll
        for (int i = 0; i < 4; i++)
#pragma unroll
            for (int j = 0; j < 4; j++)
                acc[i][j] = __builtin_amdgcn_mfma_f32_16x16x32_bf16(b[j], a[i], acc[i][j], 0, 0, 0);
    }

    // Epilogue: lane owns M-row (m0+wm+i*16+r16), cols col0..col0+3 per j.
    float4 bias4[4];
#pragma unroll
    for (int j = 0; j < 4; j++) {
        const int col0 = n0 + wn + j * 16 + quad * 4;
        if constexpr (IS_QKV) {
            const float* bp = (col0 < 1024) ? (b0 + col0)
                             : (col0 < 2048) ? (b1 + col0 - 1024)
                                             : (b2 + col0 - 2048);
            bias4[j] = *(const float4*)bp;
        } else {
            bias4[j] = *(const float4*)(b0 + col0);
        }
    }
#pragma unroll
    for (int i = 0; i < 4; i++) {
        const int grow = m0 + wm + i * 16 + r16;
#pragma unroll
        for (int j = 0; j < 4; j++) {
            const int col0 = n0 + wn + j * 16 + quad * 4;
            if constexpr (IS_QKV) {
                u16x4_t o;
                o.x = f2bf(acc[i][j][0] + bias4[j].x);
                o.y = f2bf(acc[i][j][1] + bias4[j].y);
                o.z = f2bf(acc[i][j][2] + bias4[j].z);
                o.w = f2bf(acc[i][j][3] + bias4[j].w);
                *(u16x4_t*)&Cbf[(size_t)grow * N + col0] = o;
            } else {
                float4 o;
                o.x = acc[i][j][0] + bias4[j].x;
                o.y = acc[i][j][1] + bias4[j].y;
                o.z = acc[i][j][2] + bias4[j].z;
                o.w = acc[i][j][3] + bias4[j].w;
                *(float4*)&Cf[(size_t)grow * N + col0] = o;
            }
        }
    }
}

// ---------------------------------------------------------------------------
// Attention over E=16 per (b, head).  One block per (b*NHEADS + n).
// qkv layout: [M, 3H], q at col n*128+d, k at H+..., v at 2H+...
// Writes attended bf16 [M, H] with h = n*128 + d.
// ---------------------------------------------------------------------------
__global__ __launch_bounds__(256) void k_attn(const unsigned short* __restrict__ qkv,
                                              unsigned short* __restrict__ att) {
    const int bidx = blockIdx.x;
    const int b = bidx >> 3, n = bidx & 7;
    __shared__ float qs[16][132], ks[16][132], vs[16][132];
    __shared__ float ps[16][17];
    const int t = threadIdx.x;

    {
        const int row = t >> 4, c0 = (t & 15) * 8;
        const size_t base = (size_t)(b * EEXP + row) * (3 * HDIM) + n * HEADD + c0;
        u16x8_t qv = *(const u16x8_t*)&qkv[base];
        u16x8_t kv = *(const u16x8_t*)&qkv[base + HDIM];
        u16x8_t vv = *(const u16x8_t*)&qkv[base + 2 * HDIM];
#pragma unroll
        for (int u = 0; u < 8; u++) {
            qs[row][c0 + u] = bf2f(qv[u]);
            ks[row][c0 + u] = bf2f(kv[u]);
            vs[row][c0 + u] = bf2f(vv[u]);
        }
    }
    __syncthreads();

    const int qe = t >> 4, ke = t & 15;
    float s = 0.f;
#pragma unroll 8
    for (int d = 0; d < HEADD; d += 4) {
        s += qs[qe][d] * ks[ke][d] + qs[qe][d + 1] * ks[ke][d + 1] +
             qs[qe][d + 2] * ks[ke][d + 2] + qs[qe][d + 3] * ks[ke][d + 3];
    }
    s *= 0.08838834764831845f;  // 1/sqrt(128)
    float mx = s;
#pragma unroll
    for (int off = 8; off; off >>= 1) mx = fmaxf(mx, __shfl_xor(mx, off, 16));
    const float ex = __expf(s - mx);
    float sum = ex;
#pragma unroll
    for (int off = 8; off; off >>= 1) sum += __shfl_xor(sum, off, 16);
    ps[qe][ke] = ex / sum;
    __syncthreads();

    const int dd = t & 15;
    float o[8] = {0.f, 0.f, 0.f, 0.f, 0.f, 0.f, 0.f, 0.f};
#pragma unroll
    for (int k2 = 0; k2 < EEXP; k2++) {
        const float p = ps[qe][k2];
#pragma unroll
        for (int u = 0; u < 8; u++) o[u] += p * vs[k2][dd + 16 * u];
    }
    const size_t ob = (size_t)(b * EEXP + qe) * HDIM + n * HEADD + dd;
#pragma unroll
    for (int u = 0; u < 8; u++) att[ob + 16 * u] = f2bf(o[u]);
}

// ---------------------------------------------------------------------------
// Residual + gate + blend.  One block per row.  In-place on d_out.
// ---------------------------------------------------------------------------
__global__ __launch_bounds__(256) void k_gate(const float* __restrict__ x,
                                              const float* __restrict__ wg,
                                              const float* __restrict__ bg,
                                              float* __restrict__ out) {
    const int m = blockIdx.x;
    const int e = m & (EEXP - 1);
    const int t = threadIdx.x;
    const int h = t * 4;
    const float* xr = x + (size_t)m * HDIM;
    float* orow = out + (size_t)m * HDIM;

    float4 xv = *(const float4*)(xr + h);
    float4 rv = *(const float4*)(orow + h);
    float c0 = 0.f, c1 = 0.f, c2 = 0.f, c3 = 0.f;
    if (e > 0) {
        float4 v = *(const float4*)(xr - HDIM + h);
        c0 = 0.5f * v.x; c1 = 0.5f * v.y; c2 = 0.5f * v.z; c3 = 0.5f * v.w;
    }
    if (e < EEXP - 1) {
        float4 v = *(const float4*)(xr + HDIM + h);
        c0 += 0.5f * v.x; c1 += 0.5f * v.y; c2 += 0.5f * v.z; c3 += 0.5f * v.w;
    }
    const float co0 = rv.x + c0, co1 = rv.y + c1, co2 = rv.z + c2, co3 = rv.w + c3;

    float4 w1 = *(const float4*)(wg + h);
    float4 w2 = *(const float4*)(wg + HDIM + h);
    float d = xv.x * w1.x + xv.y * w1.y + xv.z * w1.z + xv.w * w1.w +
              co0 * w2.x + co1 * w2.y + co2 * w2.z + co3 * w2.w;
#pragma unroll
    for (int off = 32; off; off >>= 1) d += __shfl_xor(d, off, 64);
    __shared__ float red[4];
    const int wv = t >> 6;
    if ((t & 63) == 0) red[wv] = d;
    __syncthreads();
    const float tot = red[0] + red[1] + red[2] + red[3] + bg[0];
    const float gate = 1.0f / (1.0f + __expf(-tot));

    float4 ov;
    ov.x = gate * co0 + (1.0f - gate) * xv.x;
    ov.y = gate * co1 + (1.0f - gate) * xv.y;
    ov.z = gate * co2 + (1.0f - gate) * xv.z;
    ov.w = gate * co3 + (1.0f - gate) * xv.w;
    *(float4*)(orow + h) = ov;
}

// ---------------------------------------------------------------------------
extern "C" void kernel_launch(void* const* d_in, const int* in_sizes, int n_in,
                              void* d_out, int out_size, void* d_ws, size_t ws_size,
                              hipStream_t stream) {
    const float* x   = (const float*)d_in[0];
    const float* lng = (const float*)d_in[1];
    const float* lnb = (const float*)d_in[2];
    const float* wq  = (const float*)d_in[3];
    const float* bq  = (const float*)d_in[4];
    const float* wk  = (const float*)d_in[5];
    const float* bk  = (const float*)d_in[6];
    const float* wv  = (const float*)d_in[7];
    const float* bv  = (const float*)d_in[8];
    const float* wo  = (const float*)d_in[9];
    const float* bo  = (const float*)d_in[10];
    const float* wg  = (const float*)d_in[11];
    const float* bg  = (const float*)d_in[12];
    float* out = (float*)d_out;

    // workspace layout (bf16 buffers), total ~344 MB
    unsigned short* wqkv = (unsigned short*)d_ws;                 // [3072,1024]
    unsigned short* wob  = wqkv + (size_t)3072 * 1024;            // [1024,1024]
    unsigned short* xn   = wob + (size_t)1024 * 1024;             // [M,1024]
    unsigned short* qkv  = xn + (size_t)MROWS * HDIM;             // [M,3072]
    unsigned short* att  = qkv + (size_t)MROWS * 3 * HDIM;        // [M,1024]

    const int WELTS = 1024 * 1024;
    k_conv4<<<4096, 256, 0, stream>>>(wq, wk, wv, wo,
                                      wqkv, wqkv + (size_t)WELTS,
                                      wqkv + (size_t)2 * WELTS, wob);

    k_prep<<<MROWS, 256, 0, stream>>>(x, lng, lnb, xn);

    k_gemm<3072, true><<<(MROWS / 128) * (3072 / 128), 256, 0, stream>>>(
        xn, wqkv, bq, bk, bv, qkv, nullptr);

    k_attn<<<BATCH * NHEADS, 256, 0, stream>>>(qkv, att);

    k_gemm<1024, false><<<(MROWS / 128) * (1024 / 128), 256, 0, stream>>>(
        att, wob, bo, nullptr, nullptr, nullptr, out);

    k_gate<<<MROWS, 256, 0, stream>>>(x, wg, bg, out);
}

// Round 3
// 797.194 us; speedup vs baseline: 1.1803x; 1.0250x over previous
//
#include <hip/hip_runtime.h>
#include <cstdint>
#include <cstddef>

// Problem dims (fixed by setup_inputs)
#define HDIM 1024
#define EEXP 16
#define BATCH 2048
#define MROWS (BATCH * EEXP)   // 32768
#define NHEADS 8
#define HEADD 128
#define KDIM 1024
#define LN_EPS 1e-5f

typedef __bf16 bf16x8_t __attribute__((ext_vector_type(8)));
typedef float f32x4_t __attribute__((ext_vector_type(4)));
typedef unsigned short u16x4_t __attribute__((ext_vector_type(4)));
typedef unsigned short u16x8_t __attribute__((ext_vector_type(8)));

__device__ __forceinline__ unsigned short f2bf(float f) {
    unsigned int u = __builtin_bit_cast(unsigned int, f);
    unsigned int r = (u + 0x7FFFu + ((u >> 16) & 1u)) >> 16;  // RNE
    return (unsigned short)r;
}
__device__ __forceinline__ float bf2f(unsigned short h) {
    unsigned int u = ((unsigned int)h) << 16;
    return __builtin_bit_cast(float, u);
}

// ---------------------------------------------------------------------------
// fp32 -> bf16 conversion for all 4 weight matrices in one launch.
// ---------------------------------------------------------------------------
__global__ __launch_bounds__(256) void k_conv4(
    const float* __restrict__ s0, const float* __restrict__ s1,
    const float* __restrict__ s2, const float* __restrict__ s3,
    unsigned short* __restrict__ d0, unsigned short* __restrict__ d1,
    unsigned short* __restrict__ d2, unsigned short* __restrict__ d3) {
    const int which = blockIdx.x >> 10;
    const int i = ((blockIdx.x & 1023) * 256 + threadIdx.x) * 4;
    const float* s = (which == 0) ? s0 : (which == 1) ? s1 : (which == 2) ? s2 : s3;
    unsigned short* d = (which == 0) ? d0 : (which == 1) ? d1 : (which == 2) ? d2 : d3;
    float4 v = *(const float4*)(s + i);
    u16x4_t o;
    o.x = f2bf(v.x); o.y = f2bf(v.y); o.z = f2bf(v.z); o.w = f2bf(v.w);
    *(u16x4_t*)(d + i) = o;
}

// ---------------------------------------------------------------------------
// comm (chain graph) + LayerNorm -> xn (bf16).  One block per row (b,e).
// ---------------------------------------------------------------------------
__global__ __launch_bounds__(256) void k_prep(const float* __restrict__ x,
                                              const float* __restrict__ lng,
                                              const float* __restrict__ lnb,
                                              unsigned short* __restrict__ xn) {
    const int m = blockIdx.x;
    const int e = m & (EEXP - 1);
    const int t = threadIdx.x;
    const int h = t * 4;
    const float* xr = x + (size_t)m * HDIM;

    float c0 = 0.f, c1 = 0.f, c2 = 0.f, c3 = 0.f;
    if (e > 0) {
        float4 v = *(const float4*)(xr - HDIM + h);
        c0 = 0.5f * v.x; c1 = 0.5f * v.y; c2 = 0.5f * v.z; c3 = 0.5f * v.w;
    }
    if (e < EEXP - 1) {
        float4 v = *(const float4*)(xr + HDIM + h);
        c0 += 0.5f * v.x; c1 += 0.5f * v.y; c2 += 0.5f * v.z; c3 += 0.5f * v.w;
    }
    float s  = c0 + c1 + c2 + c3;
    float ss = c0 * c0 + c1 * c1 + c2 * c2 + c3 * c3;
#pragma unroll
    for (int off = 32; off; off >>= 1) {
        s  += __shfl_xor(s, off, 64);
        ss += __shfl_xor(ss, off, 64);
    }
    __shared__ float red[8];
    const int wv = t >> 6;
    if ((t & 63) == 0) { red[wv] = s; red[4 + wv] = ss; }
    __syncthreads();
    s  = red[0] + red[1] + red[2] + red[3];
    ss = red[4] + red[5] + red[6] + red[7];
    const float mean = s * (1.0f / HDIM);
    const float var  = ss * (1.0f / HDIM) - mean * mean;
    const float rinv = rsqrtf(var + LN_EPS);

    float4 g = *(const float4*)(lng + h);
    float4 b = *(const float4*)(lnb + h);
    u16x4_t o;
    o.x = f2bf((c0 - mean) * rinv * g.x + b.x);
    o.y = f2bf((c1 - mean) * rinv * g.y + b.y);
    o.z = f2bf((c2 - mean) * rinv * g.z + b.z);
    o.w = f2bf((c3 - mean) * rinv * g.w + b.w);
    *(u16x4_t*)(xn + (size_t)m * HDIM + h) = o;
}

// ---------------------------------------------------------------------------
// bf16 GEMM, C[m,n] = sum_k A[m,k] * W[n,k]   (B^T layout).
// 128x128 tile, BK=64, 256 threads (4 waves, 2x2 of 64x64), mfma 16x16x32.
// - XCD supertile swizzle: xcd = blk&7 owns M-stripe [xcd*32, xcd*32+32),
//   walked in supertiles (8 mt x 12 nt for N=3072; 8 mt x 8 nt for N=1024)
//   so the concurrent per-XCD working set ~4-5 MB fits its private L2.
// - LDS 16B k-chunks XOR-swizzled by (row&7): ds_read_b128 2-way max (free).
// - MFMA operands swapped (mfma(b,a)): lane = one M-row, 4 consecutive
//   N-cols per acc group -> packed epilogue stores.
// ---------------------------------------------------------------------------
template <int N, bool IS_QKV>
__global__ __launch_bounds__(256) void k_gemm(
    const unsigned short* __restrict__ A,   // [M, K] bf16
    const unsigned short* __restrict__ Bw,  // [N, K] bf16
    const float* __restrict__ b0,           // bias (bq or bo)
    const float* __restrict__ b1,           // bk (QKV only)
    const float* __restrict__ b2,           // bv (QKV only)
    unsigned short* __restrict__ Cbf,       // QKV output
    float* __restrict__ Cf) {               // O output
    constexpr int K = KDIM;
    __shared__ unsigned short As[128 * 64];
    __shared__ unsigned short Bs[128 * 64];

    const int tid = threadIdx.x;
    // --- XCD supertile swizzle ---
    const int xcd = blockIdx.x & 7;
    const int g   = blockIdx.x >> 3;        // 0 .. grid/8-1
    int mt, nt;
    if constexpr (N == 3072) {
        const int st = g / 96, r = g % 96;  // 8 supertiles of 8x12
        mt = xcd * 32 + (st >> 1) * 8 + (r & 7);
        nt = (st & 1) * 12 + (r >> 3);
    } else {                                 // N == 1024
        const int st = g >> 6, r = g & 63;  // 4 supertiles of 8x8
        mt = xcd * 32 + st * 8 + (r & 7);
        nt = r >> 3;
    }
    const int m0 = mt * 128, n0 = nt * 128;

    const int lane = tid & 63, wave = tid >> 6;
    const int wm   = (wave >> 1) * 64, wn = (wave & 1) * 64;
    const int quad = lane >> 4, r16 = lane & 15;
    // staging: chunk c = q*256+tid -> row c>>3, phys col16 c&7; holds global
    // k-chunk (c&7)^(row&7).  LDS dest stays lane-contiguous (m104 caveat).
    const int srow = tid >> 3;               // row for q=0; +32 per q
    const int sgk  = ((tid & 7) ^ (srow & 7)) * 8;

    f32x4_t acc[4][4];
#pragma unroll
    for (int i = 0; i < 4; i++)
#pragma unroll
        for (int j = 0; j < 4; j++) acc[i][j] = f32x4_t{0.f, 0.f, 0.f, 0.f};

    f32x4_t bias4[4];
#pragma unroll
    for (int j = 0; j < 4; j++) {
        const int col0 = n0 + wn + j * 16 + quad * 4;
        const float* bp;
        if constexpr (IS_QKV) {
            bp = (col0 < 1024) ? (b0 + col0)
               : (col0 < 2048) ? (b1 + col0 - 1024)
                               : (b2 + col0 - 2048);
        } else {
            bp = b0 + col0;
        }
        bias4[j] = *(const f32x4_t*)bp;
    }

    // global row pointers for the 4 staging insts (q: row += 32)
    const unsigned short* Ag = A + (size_t)(m0 + srow) * K + sgk;
    const unsigned short* Bg = Bw + (size_t)(n0 + srow) * K + sgk;
    // ds_read swizzled chunk base for this lane (logical chunk l=h*4+quad)
    const int swz0 = ((0 * 4 + quad) ^ (r16 & 7)) * 8;
    const int swz1 = ((1 * 4 + quad) ^ (r16 & 7)) * 8;

    for (int k0 = 0; k0 < K; k0 += 64) {
        __syncthreads();  // previous iteration's LDS reads complete
#pragma unroll
        for (int q = 0; q < 4; q++) {
            __builtin_amdgcn_global_load_lds(
                (const __attribute__((address_space(1))) void*)(Ag + (size_t)(q * 32) * K + k0),
                (__attribute__((address_space(3))) void*)(As + q * 2048 + tid * 8), 16, 0, 0);
        }
#pragma unroll
        for (int q = 0; q < 4; q++) {
            __builtin_amdgcn_global_load_lds(
                (const __attribute__((address_space(1))) void*)(Bg + (size_t)(q * 32) * K + k0),
                (__attribute__((address_space(3))) void*)(Bs + q * 2048 + tid * 8), 16, 0, 0);
        }
        __syncthreads();  // tiles resident

#pragma unroll
        for (int h = 0; h < 2; h++) {
            const int swz = h ? swz1 : swz0;
            bf16x8_t a[4], b[4];
#pragma unroll
            for (int i = 0; i < 4; i++)
                a[i] = *(const bf16x8_t*)&As[(wm + i * 16 + r16) * 64 + swz];
#pragma unroll
            for (int j = 0; j < 4; j++)
                b[j] = *(const bf16x8_t*)&Bs[(wn + j * 16 + r16) * 64 + swz];
            // swapped operands: D[m = lane&15][n = quad*4 + reg]
#pragma unroll
            for (int i = 0; i < 4; i++)
#pragma unroll
                for (int j = 0; j < 4; j++)
                    acc[i][j] = __builtin_amdgcn_mfma_f32_16x16x32_bf16(b[j], a[i], acc[i][j], 0, 0, 0);
        }
    }

    // Epilogue: lane owns M-row (m0+wm+i*16+r16), 4 cols per j (packed).
#pragma unroll
    for (int i = 0; i < 4; i++) {
        const int grow = m0 + wm + i * 16 + r16;
#pragma unroll
        for (int j = 0; j < 4; j++) {
            const int col0 = n0 + wn + j * 16 + quad * 4;
            if constexpr (IS_QKV) {
                u16x4_t o;
                o.x = f2bf(acc[i][j][0] + bias4[j][0]);
                o.y = f2bf(acc[i][j][1] + bias4[j][1]);
                o.z = f2bf(acc[i][j][2] + bias4[j][2]);
                o.w = f2bf(acc[i][j][3] + bias4[j][3]);
                *(u16x4_t*)&Cbf[(size_t)grow * N + col0] = o;
            } else {
                f32x4_t o;
                o[0] = acc[i][j][0] + bias4[j][0];
                o[1] = acc[i][j][1] + bias4[j][1];
                o[2] = acc[i][j][2] + bias4[j][2];
                o[3] = acc[i][j][3] + bias4[j][3];
                *(f32x4_t*)&Cf[(size_t)grow * N + col0] = o;
            }
        }
    }
}

// ---------------------------------------------------------------------------
// Attention over E=16 per (b, head).  One block per (b*NHEADS + n).
// float4 LDS traffic throughout; packed u16x8 output stores.
// ---------------------------------------------------------------------------
__global__ __launch_bounds__(256) void k_attn(const unsigned short* __restrict__ qkv,
                                              unsigned short* __restrict__ att) {
    const int bidx = blockIdx.x;
    const int b = bidx >> 3, n = bidx & 7;
    __shared__ float qs[16][132], ks[16][132], vs[16][132];
    __shared__ float ps[16][17];
    const int t = threadIdx.x;

    {
        const int row = t >> 4, c0 = (t & 15) * 8;
        const size_t base = (size_t)(b * EEXP + row) * (3 * HDIM) + n * HEADD + c0;
        u16x8_t qv = *(const u16x8_t*)&qkv[base];
        u16x8_t kv = *(const u16x8_t*)&qkv[base + HDIM];
        u16x8_t vv = *(const u16x8_t*)&qkv[base + 2 * HDIM];
        f32x4_t q0, q1, k0, k1, v0, v1;
#pragma unroll
        for (int u = 0; u < 4; u++) {
            q0[u] = bf2f(qv[u]); q1[u] = bf2f(qv[u + 4]);
            k0[u] = bf2f(kv[u]); k1[u] = bf2f(kv[u + 4]);
            v0[u] = bf2f(vv[u]); v1[u] = bf2f(vv[u + 4]);
        }
        *(f32x4_t*)&qs[row][c0] = q0; *(f32x4_t*)&qs[row][c0 + 4] = q1;
        *(f32x4_t*)&ks[row][c0] = k0; *(f32x4_t*)&ks[row][c0 + 4] = k1;
        *(f32x4_t*)&vs[row][c0] = v0; *(f32x4_t*)&vs[row][c0 + 4] = v1;
    }
    __syncthreads();

    const int qe = t >> 4, ke = t & 15;
    float s = 0.f;
#pragma unroll
    for (int d = 0; d < HEADD; d += 4) {
        f32x4_t qv = *(const f32x4_t*)&qs[qe][d];
        f32x4_t kv = *(const f32x4_t*)&ks[ke][d];
        s += qv[0] * kv[0] + qv[1] * kv[1] + qv[2] * kv[2] + qv[3] * kv[3];
    }
    s *= 0.08838834764831845f;  // 1/sqrt(128)
    float mx = s;
#pragma unroll
    for (int off = 8; off; off >>= 1) mx = fmaxf(mx, __shfl_xor(mx, off, 16));
    const float ex = __expf(s - mx);
    float sum = ex;
#pragma unroll
    for (int off = 8; off; off >>= 1) sum += __shfl_xor(sum, off, 16);
    ps[qe][ke] = ex / sum;
    __syncthreads();

    // attended: thread owns (qe, 8 consecutive dims dd8)
    const int dd8 = (t & 15) * 8;
    float o[8] = {0.f, 0.f, 0.f, 0.f, 0.f, 0.f, 0.f, 0.f};
#pragma unroll
    for (int k2 = 0; k2 < EEXP; k2++) {
        const float p = ps[qe][k2];
        f32x4_t v0 = *(const f32x4_t*)&vs[k2][dd8];
        f32x4_t v1 = *(const f32x4_t*)&vs[k2][dd8 + 4];
        o[0] += p * v0[0]; o[1] += p * v0[1]; o[2] += p * v0[2]; o[3] += p * v0[3];
        o[4] += p * v1[0]; o[5] += p * v1[1]; o[6] += p * v1[2]; o[7] += p * v1[3];
    }
    u16x8_t ov;
#pragma unroll
    for (int u = 0; u < 8; u++) ov[u] = f2bf(o[u]);
    *(u16x8_t*)&att[(size_t)(b * EEXP + qe) * HDIM + n * HEADD + dd8] = ov;
}

// ---------------------------------------------------------------------------
// Residual + gate + blend.  One block per row.  In-place on d_out.
// ---------------------------------------------------------------------------
__global__ __launch_bounds__(256) void k_gate(const float* __restrict__ x,
                                              const float* __restrict__ wg,
                                              const float* __restrict__ bg,
                                              float* __restrict__ out) {
    const int m = blockIdx.x;
    const int e = m & (EEXP - 1);
    const int t = threadIdx.x;
    const int h = t * 4;
    const float* xr = x + (size_t)m * HDIM;
    float* orow = out + (size_t)m * HDIM;

    float4 xv = *(const float4*)(xr + h);
    float4 rv = *(const float4*)(orow + h);
    float c0 = 0.f, c1 = 0.f, c2 = 0.f, c3 = 0.f;
    if (e > 0) {
        float4 v = *(const float4*)(xr - HDIM + h);
        c0 = 0.5f * v.x; c1 = 0.5f * v.y; c2 = 0.5f * v.z; c3 = 0.5f * v.w;
    }
    if (e < EEXP - 1) {
        float4 v = *(const float4*)(xr + HDIM + h);
        c0 += 0.5f * v.x; c1 += 0.5f * v.y; c2 += 0.5f * v.z; c3 += 0.5f * v.w;
    }
    const float co0 = rv.x + c0, co1 = rv.y + c1, co2 = rv.z + c2, co3 = rv.w + c3;

    float4 w1 = *(const float4*)(wg + h);
    float4 w2 = *(const float4*)(wg + HDIM + h);
    float d = xv.x * w1.x + xv.y * w1.y + xv.z * w1.z + xv.w * w1.w +
              co0 * w2.x + co1 * w2.y + co2 * w2.z + co3 * w2.w;
#pragma unroll
    for (int off = 32; off; off >>= 1) d += __shfl_xor(d, off, 64);
    __shared__ float red[4];
    const int wv = t >> 6;
    if ((t & 63) == 0) red[wv] = d;
    __syncthreads();
    const float tot = red[0] + red[1] + red[2] + red[3] + bg[0];
    const float gate = 1.0f / (1.0f + __expf(-tot));

    float4 ov;
    ov.x = gate * co0 + (1.0f - gate) * xv.x;
    ov.y = gate * co1 + (1.0f - gate) * xv.y;
    ov.z = gate * co2 + (1.0f - gate) * xv.z;
    ov.w = gate * co3 + (1.0f - gate) * xv.w;
    *(float4*)(orow + h) = ov;
}

// ---------------------------------------------------------------------------
extern "C" void kernel_launch(void* const* d_in, const int* in_sizes, int n_in,
                              void* d_out, int out_size, void* d_ws, size_t ws_size,
                              hipStream_t stream) {
    const float* x   = (const float*)d_in[0];
    const float* lng = (const float*)d_in[1];
    const float* lnb = (const float*)d_in[2];
    const float* wq  = (const float*)d_in[3];
    const float* bq  = (const float*)d_in[4];
    const float* wk  = (const float*)d_in[5];
    const float* bk  = (const float*)d_in[6];
    const float* wv  = (const float*)d_in[7];
    const float* bv  = (const float*)d_in[8];
    const float* wo  = (const float*)d_in[9];
    const float* bo  = (const float*)d_in[10];
    const float* wg  = (const float*)d_in[11];
    const float* bg  = (const float*)d_in[12];
    float* out = (float*)d_out;

    // workspace layout (bf16 buffers), total ~344 MB
    unsigned short* wqkv = (unsigned short*)d_ws;                 // [3072,1024]
    unsigned short* wob  = wqkv + (size_t)3072 * 1024;            // [1024,1024]
    unsigned short* xn   = wob + (size_t)1024 * 1024;             // [M,1024]
    unsigned short* qkv  = xn + (size_t)MROWS * HDIM;             // [M,3072]
    unsigned short* att  = qkv + (size_t)MROWS * 3 * HDIM;        // [M,1024]

    const int WELTS = 1024 * 1024;
    k_conv4<<<4096, 256, 0, stream>>>(wq, wk, wv, wo,
                                      wqkv, wqkv + (size_t)WELTS,
                                      wqkv + (size_t)2 * WELTS, wob);

    k_prep<<<MROWS, 256, 0, stream>>>(x, lng, lnb, xn);

    k_gemm<3072, true><<<(MROWS / 128) * (3072 / 128), 256, 0, stream>>>(
        xn, wqkv, bq, bk, bv, qkv, nullptr);

    k_attn<<<BATCH * NHEADS, 256, 0, stream>>>(qkv, att);

    k_gemm<1024, false><<<(MROWS / 128) * (1024 / 128), 256, 0, stream>>>(
        att, wob, bo, nullptr, nullptr, nullptr, out);

    k_gate<<<MROWS, 256, 0, stream>>>(x, wg, bg, out);
}